// Round 1
// baseline (136.625 us; speedup 1.0000x reference)
//
#include <hip/hip_runtime.h>

typedef unsigned short ushort_t;
typedef unsigned int uint_t;

#define CIN   128
#define COUT  256
#define HH    56
#define WW    56
#define HWSZ  3136            // 56*56
#define BATCH 16
#define NPIX  50176           // 16*3136
#define KTOT  1152            // 128*9

typedef __attribute__((ext_vector_type(8))) short bf16x8;
typedef __attribute__((ext_vector_type(4))) float f32x4;

__device__ __forceinline__ ushort_t f2bf(float v) {
    union { float f; uint_t u; } c; c.f = v;
    uint_t u = c.u;
    u += 0x7FFFu + ((u >> 16) & 1u);   // RNE; inputs are finite, no NaN care
    return (ushort_t)(u >> 16);
}

// ---- prepass 1: weights OIHW fp32 -> bf16 [co][pos*128+ci]
__global__ void wt_xform(const float* __restrict__ w, ushort_t* __restrict__ out) {
    int idx = blockIdx.x * 256 + threadIdx.x;      // exact: 256*1152 = 294912
    int co  = idx / KTOT;
    int k   = idx - co * KTOT;
    int pos = k >> 7;
    int ci  = k & 127;
    out[idx] = f2bf(w[co * KTOT + ci * 9 + pos]);
}

// ---- prepass 2: input NCHW fp32 -> NHWC bf16 ([b][y][x][ci], ci contiguous)
__global__ void in_xform(const float* __restrict__ in, ushort_t* __restrict__ out) {
    __shared__ ushort_t tile[WW * 130];            // pad 130 to break bank conflicts
    int by = blockIdx.x;                           // b*56 + y
    int b  = by / HH;
    int y  = by - b * HH;
    const float* src = in + (size_t)b * CIN * HWSZ + (size_t)y * WW;
    for (int idx = threadIdx.x; idx < CIN * WW; idx += 256) {
        int ci = idx / WW;
        int x  = idx - ci * WW;                    // consecutive tid -> consecutive x (coalesced)
        tile[x * 130 + ci] = f2bf(src[(size_t)ci * HWSZ + x]);
    }
    __syncthreads();
    ushort_t* dst = out + (size_t)by * WW * CIN;
    for (int idx = threadIdx.x; idx < CIN * WW; idx += 256) {
        int x  = idx >> 7;
        int ci = idx & 127;
        dst[idx] = tile[x * 130 + ci];             // contiguous global writes
    }
}

// ---- main implicit-GEMM conv: C[co][pix] = sum_k Wt[co][k] * Ib[shift(pix,pos)][ci]
__global__ __launch_bounds__(256, 2) void conv_gemm(
    const ushort_t* __restrict__ Wt,   // [256][1152] bf16, k=(pos,ci)
    const ushort_t* __restrict__ Ib,   // [NPIX][128] bf16 NHWC
    const float* __restrict__ bias,
    float* __restrict__ out,
    const ushort_t* __restrict__ guard)
{
    __shared__ ushort_t A_lds[128 * 32];
    __shared__ ushort_t B_lds[128 * 32];

    const int tid  = threadIdx.x;
    const int wave = tid >> 6;
    const int lane = tid & 63;
    const int quad = lane >> 4;
    const int l16  = lane & 15;

    const int bm = blockIdx.x & 1;     // cout tile (0/1)
    const int bn = blockIdx.x >> 1;    // pixel tile (0..391)

    const int wm = (wave >> 1) * 64;   // wave's cout offset in tile
    const int wn = (wave & 1) * 64;    // wave's pixel offset in tile

    // staging slots: slot L = wave*128 + q*64 + lane; row = L/4, chunk c = L&3
    // LDS byte dest = L*16 (wave-uniform base + lane*16, per global_load_lds contract)
    const ushort_t* aBase[2];
    const ushort_t* pb0[2];
    int py[2], px[2];
    for (int q = 0; q < 2; ++q) {
        int slot = wave * 128 + q * 64 + lane;
        int r = slot >> 2, c = slot & 3;
        aBase[q] = Wt + (size_t)(bm * 128 + r) * KTOT + c * 8;
        int pix = bn * 128 + r;
        int b_  = pix / HWSZ;
        int rem = pix - b_ * HWSZ;
        int y_  = rem / WW;
        int x_  = rem - y_ * WW;
        py[q] = y_; px[q] = x_;
        pb0[q] = Ib + (size_t)pix * CIN + c * 8;   // ((b*56+y)*56+x)*128 == pix*128
    }

    const f32x4 zero = {0.f, 0.f, 0.f, 0.f};
    f32x4 acc[4][4];
    for (int i = 0; i < 4; ++i)
        for (int j = 0; j < 4; ++j) acc[i][j] = zero;

    for (int pos = 0; pos < 9; ++pos) {
        const int dy = pos / 3 - 1;
        const int dx = pos - (pos / 3) * 3 - 1;
        const ushort_t* bp[2];
        bool okq[2];
        for (int q = 0; q < 2; ++q) {
            int yy = py[q] + dy, xx = px[q] + dx;
            okq[q] = ((uint_t)yy < (uint_t)HH) && ((uint_t)xx < (uint_t)WW);
            bp[q]  = pb0[q] + (dy * WW + dx) * CIN;
        }
        for (int cc = 0; cc < 4; ++cc) {
            for (int q = 0; q < 2; ++q) {
                __builtin_amdgcn_global_load_lds(
                    (const __attribute__((address_space(1))) void*)(aBase[q] + pos * 128 + cc * 32),
                    (__attribute__((address_space(3))) void*)(&A_lds[(wave * 128 + q * 64) * 8]),
                    16, 0, 0);
            }
            for (int q = 0; q < 2; ++q) {
                const ushort_t* g = okq[q] ? (bp[q] + cc * 32) : guard;
                __builtin_amdgcn_global_load_lds(
                    (const __attribute__((address_space(1))) void*)g,
                    (__attribute__((address_space(3))) void*)(&B_lds[(wave * 128 + q * 64) * 8]),
                    16, 0, 0);
            }
            __syncthreads();
            bf16x8 af[4], bfr[4];
            for (int i = 0; i < 4; ++i)
                af[i] = *(const bf16x8*)&A_lds[(wm + i * 16 + l16) * 32 + quad * 8];
            for (int j = 0; j < 4; ++j)
                bfr[j] = *(const bf16x8*)&B_lds[(wn + j * 16 + l16) * 32 + quad * 8];
            for (int i = 0; i < 4; ++i)
                for (int j = 0; j < 4; ++j)
                    acc[i][j] = __builtin_amdgcn_mfma_f32_16x16x32_bf16(
                        af[i], bfr[j], acc[i][j], 0, 0, 0);
            __syncthreads();
        }
    }

    // epilogue: D row (quad*4+r) = cout, col (lane&15) = pixel (x-contiguous stores)
    int obase[4];
    for (int j = 0; j < 4; ++j) {
        int pix = bn * 128 + wn + j * 16 + l16;
        int b_  = pix / HWSZ;
        int rem = pix - b_ * HWSZ;
        obase[j] = b_ * (COUT * HWSZ) + rem;
    }
    for (int i = 0; i < 4; ++i) {
        for (int r = 0; r < 4; ++r) {
            int co = bm * 128 + wm + i * 16 + quad * 4 + r;
            float bv = bias[co];
            int coOff = co * HWSZ;
            for (int j = 0; j < 4; ++j) {
                out[(size_t)(obase[j] + coOff)] = acc[i][j][r] + bv;
            }
        }
    }
}

// ---- fallback (only if workspace is too small): direct fp32 conv
__global__ void naive_conv(const float* __restrict__ in, const float* __restrict__ w,
                           const float* __restrict__ bias, float* __restrict__ out, int total) {
    int idx = blockIdx.x * 256 + threadIdx.x;
    if (idx >= total) return;
    int x = idx % WW; int t = idx / WW;
    int y = t % HH; t /= HH;
    int co = t % COUT; int b = t / COUT;
    float s = bias[co];
    const float* wr = w + (size_t)co * KTOT;
    for (int ci = 0; ci < CIN; ++ci) {
        const float* ir = in + (size_t)(b * CIN + ci) * HWSZ;
        for (int kh = 0; kh < 3; ++kh) {
            int yy = y + kh - 1;
            if ((uint_t)yy >= (uint_t)HH) continue;
            for (int kw = 0; kw < 3; ++kw) {
                int xx = x + kw - 1;
                if ((uint_t)xx >= (uint_t)WW) continue;
                s += ir[yy * WW + xx] * wr[ci * 9 + kh * 3 + kw];
            }
        }
    }
    out[idx] = s;
}

extern "C" void kernel_launch(void* const* d_in, const int* in_sizes, int n_in,
                              void* d_out, int out_size, void* d_ws, size_t ws_size,
                              hipStream_t stream) {
    const float* tensor  = (const float*)d_in[0];
    const float* weights = (const float*)d_in[1];
    const float* bias    = (const float*)d_in[2];
    float* out = (float*)d_out;

    const size_t GUARD    = 1024;
    const size_t WT_BYTES = (size_t)COUT * KTOT * 2;   // 589824
    const size_t IB_BYTES = (size_t)NPIX * CIN * 2;    // 12845056
    const size_t NEED     = GUARD + WT_BYTES + IB_BYTES;

    if (ws_size >= NEED) {
        ushort_t* guard = (ushort_t*)d_ws;
        ushort_t* Wt    = (ushort_t*)((char*)d_ws + GUARD);
        ushort_t* Ib    = (ushort_t*)((char*)d_ws + GUARD + WT_BYTES);
        hipMemsetAsync(d_ws, 0, GUARD, stream);       // zero guard page (ws is re-poisoned 0xAA)
        wt_xform<<<(COUT * KTOT) / 256, 256, 0, stream>>>(weights, Wt);
        in_xform<<<BATCH * HH, 256, 0, stream>>>(tensor, Ib);
        conv_gemm<<<(COUT / 128) * (NPIX / 128), 256, 0, stream>>>(Wt, Ib, bias, out, guard);
    } else {
        int total = BATCH * COUT * HWSZ;
        naive_conv<<<(total + 255) / 256, 256, 0, stream>>>(tensor, weights, bias, out, total);
    }
}

// Round 2
// 134.788 us; speedup vs baseline: 1.0136x; 1.0136x over previous
//
#include <hip/hip_runtime.h>

typedef unsigned short ushort_t;
typedef unsigned int uint_t;

#define CIN   128
#define COUT  256
#define HH    56
#define WW    56
#define HWSZ  3136            // 56*56
#define BATCH 16
#define NPIX  50176           // 16*3136
#define KTOT  1152            // 128*9

typedef __attribute__((ext_vector_type(8))) short bf16x8;
typedef __attribute__((ext_vector_type(4))) float f32x4;

__device__ __forceinline__ ushort_t f2bf(float v) {
    union { float f; uint_t u; } c; c.f = v;
    uint_t u = c.u;
    u += 0x7FFFu + ((u >> 16) & 1u);   // RNE; inputs finite
    return (ushort_t)(u >> 16);
}

// ---- fused prepass:
//  blocks [0,784):   input NCHW fp32 -> NHWC bf16, 128ci x 64hw tile transpose
//  blocks [784,1040): weight OIHW fp32 -> bf16 [co][pos*128+ci], one co per block
//  block 784 also zeroes the 16-byte guard page.
__global__ __launch_bounds__(256) void prep(
    const float* __restrict__ tensor, const float* __restrict__ weights,
    ushort_t* __restrict__ Ib, ushort_t* __restrict__ Wt, ushort_t* __restrict__ guard)
{
    __shared__ ushort_t lds[8704];     // input path: [64 hw][136 ci-padded]; weight path: 1152
    const int tid = threadIdx.x;

    if (blockIdx.x < 784) {
        int t   = blockIdx.x;
        int b   = t / 49;
        int hwt = t - b * 49;
        int hw0 = hwt * 64;
        const float* src = tensor + (size_t)b * CIN * HWSZ + hw0;
        // load 2048 float4 (ci-major, hw fastest): coalesced 256B per 16 lanes
        for (int k = 0; k < 8; ++k) {
            int f  = tid + k * 256;          // [0,2048)
            int ci = f >> 4;                 // 16 float4 per 64-hw row
            int ho = (f & 15) * 4;
            float4 v = *(const float4*)(src + (size_t)ci * HWSZ + ho);
            lds[(ho + 0) * 136 + ci] = f2bf(v.x);
            lds[(ho + 1) * 136 + ci] = f2bf(v.y);
            lds[(ho + 2) * 136 + ci] = f2bf(v.z);
            lds[(ho + 3) * 136 + ci] = f2bf(v.w);
        }
        __syncthreads();
        ushort_t* dst = Ib + ((size_t)b * HWSZ + hw0) * CIN;
        // store 1024 ushort8 (hw-major, ci fastest): 16B vector stores, coalesced
        for (int k = 0; k < 4; ++k) {
            int s   = tid + k * 256;         // [0,1024)
            int ho  = s >> 4;                // 16 chunks of 8 ci per 128-ci row
            int cio = (s & 15) * 8;
            bf16x8 v = *(const bf16x8*)&lds[ho * 136 + cio];   // 272B rows: 16B-aligned
            *(bf16x8*)(dst + ho * 128 + cio) = v;
        }
    } else {
        int co = blockIdx.x - 784;
        const float* src = weights + (size_t)co * KTOT;
        for (int k = 0; k < 5; ++k) {
            int idx = tid + k * 256;
            if (idx < KTOT) {
                int ci  = idx / 9;
                int pos = idx - ci * 9;
                lds[pos * 128 + ci] = f2bf(src[idx]);   // coalesced fp32 read
            }
        }
        __syncthreads();
        ushort_t* dst = Wt + (size_t)co * KTOT;
        for (int k = 0; k < 5; ++k) {
            int idx = tid + k * 256;
            if (idx < KTOT) dst[idx] = lds[idx];        // coalesced bf16 write
        }
        if (blockIdx.x == 784 && tid < 8) guard[tid] = 0;
    }
}

// ---- main implicit-GEMM conv: C[co][pix] = sum_k Wt[co][k] * Ib[shift(pix,pos)][ci]
// BK=64 per barrier pair: two 128x32 panels staged, 32 MFMA per sync pair.
__global__ __launch_bounds__(256, 4) void conv_gemm(
    const ushort_t* __restrict__ Wt,   // [256][1152] bf16, k=(pos,ci)
    const ushort_t* __restrict__ Ib,   // [NPIX][128] bf16 NHWC
    const float* __restrict__ bias,
    float* __restrict__ out,
    const ushort_t* __restrict__ guard)
{
    __shared__ ushort_t A_lds[2 * 128 * 32];   // [panel][row][k32]
    __shared__ ushort_t B_lds[2 * 128 * 32];

    const int tid  = threadIdx.x;
    const int wave = tid >> 6;
    const int lane = tid & 63;
    const int quad = lane >> 4;
    const int l16  = lane & 15;

    const int bm = blockIdx.x & 1;     // cout tile (0/1)
    const int bn = blockIdx.x >> 1;    // pixel tile (0..391)

    const int wm = (wave >> 1) * 64;   // wave's cout offset in tile
    const int wn = (wave & 1) * 64;    // wave's pixel offset in tile

    // staging slots: slot L = wave*128 + q*64 + lane; row = L/4, chunk c = L&3
    const ushort_t* aBase[2];
    const ushort_t* pb0[2];
    int py[2], px[2];
    for (int q = 0; q < 2; ++q) {
        int slot = wave * 128 + q * 64 + lane;
        int r = slot >> 2, c = slot & 3;
        aBase[q] = Wt + (size_t)(bm * 128 + r) * KTOT + c * 8;
        int pix = bn * 128 + r;
        int b_  = pix / HWSZ;
        int rem = pix - b_ * HWSZ;
        int y_  = rem / WW;
        int x_  = rem - y_ * WW;
        py[q] = y_; px[q] = x_;
        pb0[q] = Ib + (size_t)pix * CIN + c * 8;
    }
    const int ldsOff = (wave * 128) * 8;   // ushort offset of this wave's q=0 slot group

    const f32x4 zero = {0.f, 0.f, 0.f, 0.f};
    f32x4 acc[4][4];
    for (int i = 0; i < 4; ++i)
        for (int j = 0; j < 4; ++j) acc[i][j] = zero;

    for (int pos = 0; pos < 9; ++pos) {
        const int dy = pos / 3 - 1;
        const int dx = pos - (pos / 3) * 3 - 1;
        const ushort_t* bp[2];
        bool okq[2];
        for (int q = 0; q < 2; ++q) {
            int yy = py[q] + dy, xx = px[q] + dx;
            okq[q] = ((uint_t)yy < (uint_t)HH) && ((uint_t)xx < (uint_t)WW);
            bp[q]  = pb0[q] + (dy * WW + dx) * CIN;
        }
        for (int cc2 = 0; cc2 < 2; ++cc2) {
            for (int p = 0; p < 2; ++p) {
                const int cc = cc2 * 2 + p;
                for (int q = 0; q < 2; ++q) {
                    __builtin_amdgcn_global_load_lds(
                        (const __attribute__((address_space(1))) void*)(aBase[q] + pos * 128 + cc * 32),
                        (__attribute__((address_space(3))) void*)(&A_lds[p * 4096 + ldsOff + q * 512]),
                        16, 0, 0);
                }
                for (int q = 0; q < 2; ++q) {
                    const ushort_t* g = okq[q] ? (bp[q] + cc * 32) : guard;
                    __builtin_amdgcn_global_load_lds(
                        (const __attribute__((address_space(1))) void*)g,
                        (__attribute__((address_space(3))) void*)(&B_lds[p * 4096 + ldsOff + q * 512]),
                        16, 0, 0);
                }
            }
            __syncthreads();
            for (int p = 0; p < 2; ++p) {
                bf16x8 af[4], bfr[4];
                for (int i = 0; i < 4; ++i)
                    af[i] = *(const bf16x8*)&A_lds[p * 4096 + (wm + i * 16 + l16) * 32 + quad * 8];
                for (int j = 0; j < 4; ++j)
                    bfr[j] = *(const bf16x8*)&B_lds[p * 4096 + (wn + j * 16 + l16) * 32 + quad * 8];
                for (int i = 0; i < 4; ++i)
                    for (int j = 0; j < 4; ++j)
                        acc[i][j] = __builtin_amdgcn_mfma_f32_16x16x32_bf16(
                            af[i], bfr[j], acc[i][j], 0, 0, 0);
            }
            __syncthreads();
        }
    }

    // epilogue: D row (quad*4+r) = cout, col (lane&15) = pixel (x-contiguous stores)
    int obase[4];
    for (int j = 0; j < 4; ++j) {
        int pix = bn * 128 + wn + j * 16 + l16;
        int b_  = pix / HWSZ;
        int rem = pix - b_ * HWSZ;
        obase[j] = b_ * (COUT * HWSZ) + rem;
    }
    for (int i = 0; i < 4; ++i) {
        for (int r = 0; r < 4; ++r) {
            int co = bm * 128 + wm + i * 16 + quad * 4 + r;
            float bv = bias[co];
            int coOff = co * HWSZ;
            for (int j = 0; j < 4; ++j) {
                out[(size_t)(obase[j] + coOff)] = acc[i][j][r] + bv;
            }
        }
    }
}

// ---- fallback (only if workspace is too small): direct fp32 conv
__global__ void naive_conv(const float* __restrict__ in, const float* __restrict__ w,
                           const float* __restrict__ bias, float* __restrict__ out, int total) {
    int idx = blockIdx.x * 256 + threadIdx.x;
    if (idx >= total) return;
    int x = idx % WW; int t = idx / WW;
    int y = t % HH; t /= HH;
    int co = t % COUT; int b = t / COUT;
    float s = bias[co];
    const float* wr = w + (size_t)co * KTOT;
    for (int ci = 0; ci < CIN; ++ci) {
        const float* ir = in + (size_t)(b * CIN + ci) * HWSZ;
        for (int kh = 0; kh < 3; ++kh) {
            int yy = y + kh - 1;
            if ((uint_t)yy >= (uint_t)HH) continue;
            for (int kw = 0; kw < 3; ++kw) {
                int xx = x + kw - 1;
                if ((uint_t)xx >= (uint_t)WW) continue;
                s += ir[yy * WW + xx] * wr[ci * 9 + kh * 3 + kw];
            }
        }
    }
    out[idx] = s;
}

extern "C" void kernel_launch(void* const* d_in, const int* in_sizes, int n_in,
                              void* d_out, int out_size, void* d_ws, size_t ws_size,
                              hipStream_t stream) {
    const float* tensor  = (const float*)d_in[0];
    const float* weights = (const float*)d_in[1];
    const float* bias    = (const float*)d_in[2];
    float* out = (float*)d_out;

    const size_t GUARD    = 1024;
    const size_t WT_BYTES = (size_t)COUT * KTOT * 2;   // 589824
    const size_t IB_BYTES = (size_t)NPIX * CIN * 2;    // 12845056
    const size_t NEED     = GUARD + WT_BYTES + IB_BYTES;

    if (ws_size >= NEED) {
        ushort_t* guard = (ushort_t*)d_ws;
        ushort_t* Wt    = (ushort_t*)((char*)d_ws + GUARD);
        ushort_t* Ib    = (ushort_t*)((char*)d_ws + GUARD + WT_BYTES);
        prep<<<784 + COUT, 256, 0, stream>>>(tensor, weights, Ib, Wt, guard);
        conv_gemm<<<(COUT / 128) * (NPIX / 128), 256, 0, stream>>>(Wt, Ib, bias, out, guard);
    } else {
        int total = BATCH * COUT * HWSZ;
        naive_conv<<<(total + 255) / 256, 256, 0, stream>>>(tensor, weights, bias, out, total);
    }
}